// Round 1
// baseline (288.618 us; speedup 1.0000x reference)
//
#include <hip/hip_runtime.h>

#define B_SZ 4
#define SEQ  4096
#define DM   1024
#define DSTATE 16
#define ROWS (B_SZ*SEQ)   // 16384

typedef unsigned short u16;
typedef __attribute__((ext_vector_type(8))) short   s16x8;   // 8 bf16 (4 VGPRs)
typedef __attribute__((ext_vector_type(4))) float   f32x4;
typedef __attribute__((ext_vector_type(4))) u16     u16x4;

__device__ inline float bf2f(u16 u) {
    unsigned v = ((unsigned)u) << 16;
    float f; __builtin_memcpy(&f, &v, 4); return f;
}
__device__ inline u16 f2bf(float f) {
    unsigned u; __builtin_memcpy(&u, &f, 4);
    return (u16)((u + 0x7FFFu + ((u >> 16) & 1u)) >> 16);   // RNE
}
__device__ inline f32x4 mfma16(s16x8 a, s16x8 b, f32x4 c) {
    return __builtin_amdgcn_mfma_f32_16x16x32_bf16(a, b, c, 0, 0, 0);
}
// async global->LDS, 16B per lane, dest = wave-uniform base + lane*16
__device__ inline void gl_lds16(const u16* g, u16* l) {
    __builtin_amdgcn_global_load_lds(
        (const __attribute__((address_space(1))) unsigned int*)g,
        (__attribute__((address_space(3))) unsigned int*)l, 16, 0, 0);
}

// ---------------------------------------------------------------------------
// K0a: x fp32 -> (xh, xl) bf16 split.  x = xh + xl + O(2^-18 |x|)
// ---------------------------------------------------------------------------
__global__ __launch_bounds__(256) void k_cvt_split(
    const float* __restrict__ in, u16* __restrict__ oh, u16* __restrict__ ol, int n4)
{
    int i = blockIdx.x * 256 + threadIdx.x;
    if (i < n4) {
        f32x4 v = ((const f32x4*)in)[i];
        u16x4 h, l;
#pragma unroll
        for (int c = 0; c < 4; c++) {
            h[c] = f2bf(v[c]);
            l[c] = f2bf(v[c] - bf2f(h[c]));
        }
        ((u16x4*)oh)[i] = h;
        ((u16x4*)ol)[i] = l;
    }
}

// ---------------------------------------------------------------------------
// K0b: weight conversions in one launch.
// ---------------------------------------------------------------------------
__global__ __launch_bounds__(256) void k_cvt_w(
    const float* __restrict__ gw, const float* __restrict__ Bw,
    const float* __restrict__ Cw, u16* __restrict__ gwb,
    u16* __restrict__ bwh, u16* __restrict__ bwl,
    u16* __restrict__ cwh, u16* __restrict__ cwl)
{
    int blk = blockIdx.x;
    if (blk < 1024) {
        int i = blk * 256 + threadIdx.x;
        f32x4 v = ((const f32x4*)gw)[i];
        u16x4 o;
#pragma unroll
        for (int c = 0; c < 4; c++) o[c] = f2bf(v[c]);
        ((u16x4*)gwb)[i] = o;
    } else {
        int isC = (blk >= 1040);
        const float* src = isC ? Cw : Bw;
        u16* dh = isC ? cwh : bwh;
        u16* dl = isC ? cwl : bwl;
        int i = (blk - (isC ? 1040 : 1024)) * 256 + threadIdx.x;
        f32x4 v = ((const f32x4*)src)[i];
        u16x4 h, l;
#pragma unroll
        for (int c = 0; c < 4; c++) {
            h[c] = f2bf(v[c]);
            l[c] = f2bf(v[c] - bf2f(h[c]));
        }
        ((u16x4*)dh)[i] = h;
        ((u16x4*)dl)[i] = l;
    }
}

// ---------------------------------------------------------------------------
// K1: Bx/Cx = x @ B_w^T, x @ C_w^T, 3-pass split-bf16 MFMA (fp32-grade).
// ---------------------------------------------------------------------------
__global__ __launch_bounds__(64) void k_bxcx(
    const u16* __restrict__ xh, const u16* __restrict__ xl,
    const u16* __restrict__ bwh, const u16* __restrict__ bwl,
    const u16* __restrict__ cwh, const u16* __restrict__ cwl,
    float* __restrict__ Bx, float* __restrict__ Cx)
{
    int lane = threadIdx.x;
    int lo = lane & 15, hi = lane >> 4;
    int m0 = blockIdx.x * 16;
    f32x4 accB = {}, accC = {};
    for (int k0 = 0; k0 < DM; k0 += 32) {
        size_t woff = (size_t)lo * DM + k0 + hi * 8;
        s16x8 bh = *(const s16x8*)(bwh + woff);
        s16x8 bl = *(const s16x8*)(bwl + woff);
        s16x8 ch = *(const s16x8*)(cwh + woff);
        s16x8 cl = *(const s16x8*)(cwl + woff);
        size_t aoff = (size_t)(m0 + lo) * DM + k0 + hi * 8;
        s16x8 ah = *(const s16x8*)(xh + aoff);
        s16x8 al = *(const s16x8*)(xl + aoff);
        accB = mfma16(ah, bh, accB);
        accB = mfma16(al, bh, accB);
        accB = mfma16(ah, bl, accB);
        accC = mfma16(ah, ch, accC);
        accC = mfma16(al, ch, accC);
        accC = mfma16(ah, cl, accC);
    }
#pragma unroll
    for (int r = 0; r < 4; r++) {
        int m = m0 + hi * 4 + r;
        Bx[(size_t)m * DSTATE + lo] = accB[r];
        Cx[(size_t)m * DSTATE + lo] = accC[r];
    }
}

// ---------------------------------------------------------------------------
// K2: gate = sigmoid(x @ gate_w^T + gate_b), fp32 out (into d_out).
// ---------------------------------------------------------------------------
#define BM 128
#define BN 128
#define BK 64

__global__ __launch_bounds__(256) void k_gate(
    const u16* __restrict__ xh, const u16* __restrict__ gwb,
    const float* __restrict__ gb, float* __restrict__ gate)
{
    __shared__ u16 sA[BM * BK], sB[BN * BK];   // 16 KB + 16 KB
    int tid = threadIdx.x;
    int wv = tid >> 6, lane = tid & 63;
    int lo = lane & 15, hi = lane >> 4;
    int m0 = blockIdx.x * BM;
    int n0 = blockIdx.y * BN;

    int r_in = lane >> 3;
    int p    = lane & 7;
    int c    = p ^ r_in;

    int mrow = (wv & 1) * 64;
    int ncol = (wv >> 1) * 64;

    f32x4 acc[4][4] = {};
    for (int k0 = 0; k0 < DM; k0 += BK) {
        __syncthreads();
#pragma unroll
        for (int q = 0; q < 4; q++) {
            int r = (wv * 4 + q) * 8 + r_in;
            size_t goff = (size_t)r * DM + k0 + c * 8;
            gl_lds16(xh  + (size_t)m0 * DM + goff, &sA[(wv * 4 + q) * 512]);
            gl_lds16(gwb + (size_t)n0 * DM + goff, &sB[(wv * 4 + q) * 512]);
        }
        __syncthreads();
#pragma unroll
        for (int kk = 0; kk < 2; kk++) {
            s16x8 bfr[4], afr[4];
#pragma unroll
            for (int j = 0; j < 4; j++) {
                int rb = ncol + j * 16 + lo;
                int pc = (kk * 4 + hi) ^ (rb & 7);
                bfr[j] = *(const s16x8*)&sB[rb * BK + pc * 8];
            }
#pragma unroll
            for (int i = 0; i < 4; i++) {
                int ra = mrow + i * 16 + lo;
                int pc = (kk * 4 + hi) ^ (ra & 7);
                afr[i] = *(const s16x8*)&sA[ra * BK + pc * 8];
            }
#pragma unroll
            for (int i = 0; i < 4; i++)
#pragma unroll
                for (int j = 0; j < 4; j++)
                    acc[i][j] = mfma16(afr[i], bfr[j], acc[i][j]);
        }
    }
#pragma unroll
    for (int i = 0; i < 4; i++)
#pragma unroll
        for (int r = 0; r < 4; r++) {
            int m = m0 + mrow + i * 16 + hi * 4 + r;
#pragma unroll
            for (int j = 0; j < 4; j++) {
                int n = n0 + ncol + j * 16 + lo;
                float v = acc[i][j][r] + gb[n];
                gate[(size_t)m * DM + n] = 1.0f / (1.0f + __expf(-v));
            }
        }
}

// ---------------------------------------------------------------------------
// K3: windowed scan + gate-combine + fused LayerNorm, 1024-thread blocks.
// Block covers ALL of DM (d = threadIdx.x) for one 64-step chunk of one batch:
// grid (SEQ/64, B) = 256 blocks, 16 waves each -> 16 waves/CU.
// After each 4-row group, block-wide reduce (shuffle + LDS) gives mean/var;
// LN applied in-register; final output written directly (k_ln eliminated).
// gate (in d_out) is read-then-overwritten by the same thread.
// Next group's x/gate loads are issued BEFORE current compute to hide latency.
// ---------------------------------------------------------------------------
#define CHUNK_L 64
#define LOOKBACK 32

__global__ __launch_bounds__(1024) void k_scan_ln(
    const float* __restrict__ x, const float* __restrict__ A_log,
    const float* __restrict__ Bx, const float* __restrict__ Cx,
    const float* __restrict__ Dvec, const float* __restrict__ gamma,
    const float* __restrict__ beta, float* out)
{
    __shared__ float sBx[(CHUNK_L + LOOKBACK) * DSTATE];   // 6 KB
    __shared__ float sCx[(CHUNK_L + LOOKBACK) * DSTATE];   // 6 KB
    __shared__ float sRed[16 * 8];                         // 16 waves x (s[4],s2[4])
    __shared__ float sStat[8];                             // mu[4], rs[4]

    int d = threadIdx.x;          // 0..1023 == channel
    int wv = d >> 6, lane = d & 63;
    int b = blockIdx.y;
    int t0 = blockIdx.x * CHUNK_L;
    int tstart = t0 - LOOKBACK; if (tstart < 0) tstart = 0;
    int lb = t0 - tstart;         // 0 or 32
    int nv = (lb + CHUNK_L) * (DSTATE / 4);   // <= 384

    const f32x4* gB = (const f32x4*)(Bx + ((size_t)b * SEQ + tstart) * DSTATE);
    const f32x4* gC = (const f32x4*)(Cx + ((size_t)b * SEQ + tstart) * DSTATE);
    if (d < nv) {
        ((f32x4*)sBx)[d] = gB[d];
        ((f32x4*)sCx)[d] = gC[d];
    }

    float A[DSTATE], h[DSTATE];
    const f32x4* ga = (const f32x4*)(A_log + (size_t)d * DSTATE);
#pragma unroll
    for (int q = 0; q < 4; q++) {
        f32x4 av = ga[q];
#pragma unroll
        for (int c = 0; c < 4; c++) {
            A[q * 4 + c] = expf(av[c]);
            h[q * 4 + c] = 0.0f;
        }
    }
    float Dd  = Dvec[d];
    float gam = gamma[d];
    float bet = beta[d];
    __syncthreads();

    // Phase 1: lookback (state warm-up, no output).
    const float* xp = x + ((size_t)b * SEQ + tstart) * DM + d;
    for (int u = 0; u < lb; u += 4) {
        float xv[4];
#pragma unroll
        for (int q = 0; q < 4; q++) xv[q] = xp[(size_t)(u + q) * DM];
#pragma unroll
        for (int q = 0; q < 4; q++) {
            int idx = u + q;
#pragma unroll
            for (int n = 0; n < DSTATE; n++)
                h[n] = h[n] * A[n] + sBx[idx * DSTATE + n] * xv[q];
        }
    }

    // Phase 2: output steps with fused gate-combine + LayerNorm.
    const float* xp2 = x + ((size_t)b * SEQ + t0) * DM + d;
    float* gp = out + ((size_t)b * SEQ + t0) * DM + d;

    float xv[4], gv[4];
#pragma unroll
    for (int q = 0; q < 4; q++) {
        xv[q] = xp2[(size_t)q * DM];
        gv[q] = gp [(size_t)q * DM];
    }

    for (int u = 0; u < CHUNK_L; u += 4) {
        // prefetch next group (issued before compute; consumed next iter)
        float xn[4], gn[4];
        if (u + 4 < CHUNK_L) {
#pragma unroll
            for (int q = 0; q < 4; q++) {
                xn[q] = xp2[(size_t)(u + 4 + q) * DM];
                gn[q] = gp [(size_t)(u + 4 + q) * DM];
            }
        }

        float ov[4];
#pragma unroll
        for (int q = 0; q < 4; q++) {
            int idx = lb + u + q;
            float y = 0.0f;
#pragma unroll
            for (int n = 0; n < DSTATE; n++) {
                h[n] = h[n] * A[n] + sBx[idx * DSTATE + n] * xv[q];
                y += h[n] * sCx[idx * DSTATE + n];
            }
            float yv = y + Dd * xv[q];
            ov[q] = gv[q] * yv + (1.0f - gv[q]) * xv[q];
        }

        // LayerNorm stats: wave butterfly, then cross-wave via LDS.
        float s[4], s2[4];
#pragma unroll
        for (int q = 0; q < 4; q++) { s[q] = ov[q]; s2[q] = ov[q] * ov[q]; }
#pragma unroll
        for (int off = 32; off > 0; off >>= 1) {
#pragma unroll
            for (int q = 0; q < 4; q++) {
                s[q]  += __shfl_xor(s[q],  off);
                s2[q] += __shfl_xor(s2[q], off);
            }
        }
        if (lane == 0) {
#pragma unroll
            for (int q = 0; q < 4; q++) {
                sRed[wv * 8 + q]     = s[q];
                sRed[wv * 8 + 4 + q] = s2[q];
            }
        }
        __syncthreads();
        if (d < 4) {
            float ts = 0.0f, ts2 = 0.0f;
#pragma unroll
            for (int w = 0; w < 16; w++) {
                ts  += sRed[w * 8 + d];
                ts2 += sRed[w * 8 + 4 + d];
            }
            float mu  = ts  * (1.0f / DM);
            float var = ts2 * (1.0f / DM) - mu * mu;
            sStat[d]     = mu;
            sStat[4 + d] = rsqrtf(var + 1e-5f);
        }
        __syncthreads();
#pragma unroll
        for (int q = 0; q < 4; q++) {
            float o = (ov[q] - sStat[q]) * sStat[4 + q] * gam + bet;
            gp[(size_t)(u + q) * DM] = o;
        }
        if (u + 4 < CHUNK_L) {
#pragma unroll
            for (int q = 0; q < 4; q++) { xv[q] = xn[q]; gv[q] = gn[q]; }
        }
    }
}

// ---------------------------------------------------------------------------
extern "C" void kernel_launch(void* const* d_in, const int* in_sizes, int n_in,
                              void* d_out, int out_size, void* d_ws, size_t ws_size,
                              hipStream_t stream)
{
    const float* x     = (const float*)d_in[0];
    const float* A_log = (const float*)d_in[1];
    const float* Bw    = (const float*)d_in[2];
    const float* Cw    = (const float*)d_in[3];
    const float* Dv    = (const float*)d_in[4];
    const float* gw    = (const float*)d_in[5];
    const float* gb    = (const float*)d_in[6];
    const float* gam   = (const float*)d_in[7];
    const float* bet   = (const float*)d_in[8];
    float* out = (float*)d_out;   // reused: gate (fp32) -> final (LN'd in k_scan_ln)

    char* ws = (char*)d_ws;
    u16*   xh  = (u16*)  ws;                             // 32 MB
    u16*   xl  = (u16*)  (ws + (32u << 20));             // 32 MB
    u16*   gwb = (u16*)  (ws + (64u << 20));             // 2 MB
    u16*   bwh = (u16*)  (ws + (66u << 20));             // 32 KB
    u16*   bwl = (u16*)  (ws + (66u << 20) + (32u << 10));
    u16*   cwh = (u16*)  (ws + (66u << 20) + (64u << 10));
    u16*   cwl = (u16*)  (ws + (66u << 20) + (96u << 10));
    float* Bx  = (float*)(ws + (67u << 20));             // 1 MB
    float* Cx  = (float*)(ws + (68u << 20));             // 1 MB

    k_cvt_split<<<ROWS * DM / 4 / 256, 256, 0, stream>>>(x, xh, xl, ROWS * DM / 4);
    k_cvt_w<<<1056, 256, 0, stream>>>(gw, Bw, Cw, gwb, bwh, bwl, cwh, cwl);
    k_bxcx<<<ROWS / 16, 64, 0, stream>>>(xh, xl, bwh, bwl, cwh, cwl, Bx, Cx);
    k_gate<<<dim3(ROWS / BM, DM / BN), 256, 0, stream>>>(xh, gwb, gb, out);
    k_scan_ln<<<dim3(SEQ / CHUNK_L, B_SZ), 1024, 0, stream>>>(
        x, A_log, Bx, Cx, Dv, gam, bet, out);
}